// Round 5
// baseline (224.461 us; speedup 1.0000x reference)
//
#include <hip/hip_runtime.h>
#include <math.h>

#define NSEG 7320
#define NLON 120
#define HIDN 128
#define ECH  16     // entries per k2 block chunk (R0-proven)
#define NCH  33     // 33*16 = 528-entry cap per row (max row ~520)

// ---------------------------------------------------------------------------
// K1: grp 0-11: LN0 + QKV projection into interleaved per-head layout
// [4][NSEG][16] (grp = mm*4 + head, 16 channels per thread) so k2 reads one
// 64B line per neighbor point: 4x dwordx4 @ 1KB/request (R5: request WIDTH is
// the binding resource — per-CU miss queue caps request COUNT, R0/R2/R3/R4
// all plateaued at ~256B-requests x ~20/CU regardless of waves/ILP/atomics).
// grp 12: meta {hi*120, dl, qw bits, ho} + per-lat-row CSR offsets.
// grp 13-14: zero num[64][NSEG]+den[4][NSEG] (contiguous, float4 stride loop).
// ---------------------------------------------------------------------------
__global__ __launch_bounds__(64) void k1_ln_qkv(
    const float* __restrict__ x,  const float* __restrict__ wq,
    const float* __restrict__ wk, const float* __restrict__ wv,
    const float* __restrict__ g,  const float* __restrict__ b,
    const int* __restrict__ out_idx, const int* __restrict__ in_idx,
    const float* __restrict__ qw, int E,
    float* __restrict__ q_i, float* __restrict__ k_i, float* __restrict__ v_i,
    int* __restrict__ row_start, int4* __restrict__ meta,
    float4* __restrict__ zbase)
{
    const int lane = threadIdx.x;
    const int tile = blockIdx.x;
    const int grp  = blockIdx.y;

    if (grp >= 13) {                       // zero num+den: 68*NSEG floats
        const int n4 = (68 * NSEG) / 4;
        for (int i = ((grp - 13) * 115 + tile) * 64 + lane; i < n4; i += 2 * 115 * 64)
            zbase[i] = make_float4(0.f, 0.f, 0.f, 0.f);
        return;
    }
    if (grp == 12) {                       // meta + row_start build
        for (int e = tile * 64 + lane; e < E; e += 115 * 64) {
            int ho = out_idx[e * NLON] / NLON;
            if (e == 0) {
                row_start[ho] = 0;
            } else {
                int hp = out_idx[(e - 1) * NLON] / NLON;
                if (hp != ho) row_start[ho] = e;
            }
            if (e == E - 1) row_start[ho + 1] = E;
            int i0 = in_idx[e * NLON];     // wo = 0 column: hi*120 + dl
            int hi = i0 / NLON;
            int dl = i0 - hi * NLON;
            meta[e] = make_int4(hi * NLON, dl, __float_as_int(qw[i0]), ho);
        }
        return;
    }

    const int n = tile * 64 + lane;
    if (n >= NSEG) return;

    float xv[64];
    float s = 0.f, s2 = 0.f;
#pragma unroll
    for (int c = 0; c < 64; ++c) { float t = x[c * NSEG + n]; xv[c] = t; s += t; s2 += t * t; }
    float mean = s * 0.015625f;
    float var  = s2 * 0.015625f - mean * mean;
    float rstd = rsqrtf(var + 1e-6f);
#pragma unroll
    for (int c = 0; c < 64; ++c) xv[c] = (xv[c] - mean) * rstd * g[c] + b[c];

    const int mm   = grp >> 2;             // 0=q 1=k 2=v
    const int head = grp & 3;
    const float* __restrict__ w = (mm == 0) ? wq : (mm == 1) ? wk : wv;
    float* __restrict__ dst = (mm == 0) ? q_i : (mm == 1) ? k_i : v_i;
    const float scale = (mm == 0) ? 0.25f : 1.0f;

    float acc[16];
#pragma unroll
    for (int j = 0; j < 16; ++j) {
        const float* __restrict__ wr = w + (head * 16 + j) * 64;
        float a = 0.f;
#pragma unroll
        for (int c = 0; c < 64; ++c) a += wr[c] * xv[c];
        acc[j] = a * scale;
    }

    float4* __restrict__ dp = (float4*)(dst + (((size_t)head * NSEG + n) << 4));
    dp[0] = make_float4(acc[0],  acc[1],  acc[2],  acc[3]);
    dp[1] = make_float4(acc[4],  acc[5],  acc[6],  acc[7]);
    dp[2] = make_float4(acc[8],  acc[9],  acc[10], acc[11]);
    dp[3] = make_float4(acc[12], acc[13], acc[14], acc[15]);
}

// ---------------------------------------------------------------------------
// helpers for k2
// ---------------------------------------------------------------------------
__device__ __forceinline__ float dot16(
    const float4 q0, const float4 q1, const float4 q2, const float4 q3,
    const float4 k0, const float4 k1, const float4 k2, const float4 k3)
{
    float s = q0.x * k0.x;
    s = fmaf(q0.y, k0.y, s); s = fmaf(q0.z, k0.z, s); s = fmaf(q0.w, k0.w, s);
    s = fmaf(q1.x, k1.x, s); s = fmaf(q1.y, k1.y, s); s = fmaf(q1.z, k1.z, s); s = fmaf(q1.w, k1.w, s);
    s = fmaf(q2.x, k2.x, s); s = fmaf(q2.y, k2.y, s); s = fmaf(q2.z, k2.z, s); s = fmaf(q2.w, k2.w, s);
    s = fmaf(q3.x, k3.x, s); s = fmaf(q3.y, k3.y, s); s = fmaf(q3.z, k3.z, s); s = fmaf(q3.w, k3.w, s);
    return s;
}

__device__ __forceinline__ void pv16(
    float w, const float4 v0, const float4 v1, const float4 v2, const float4 v3,
    float* __restrict__ acc)
{
    acc[0]  = fmaf(w, v0.x, acc[0]);  acc[1]  = fmaf(w, v0.y, acc[1]);
    acc[2]  = fmaf(w, v0.z, acc[2]);  acc[3]  = fmaf(w, v0.w, acc[3]);
    acc[4]  = fmaf(w, v1.x, acc[4]);  acc[5]  = fmaf(w, v1.y, acc[5]);
    acc[6]  = fmaf(w, v1.z, acc[6]);  acc[7]  = fmaf(w, v1.w, acc[7]);
    acc[8]  = fmaf(w, v2.x, acc[8]);  acc[9]  = fmaf(w, v2.y, acc[9]);
    acc[10] = fmaf(w, v2.z, acc[10]); acc[11] = fmaf(w, v2.w, acc[11]);
    acc[12] = fmaf(w, v3.x, acc[12]); acc[13] = fmaf(w, v3.y, acc[13]);
    acc[14] = fmaf(w, v3.z, acc[14]); acc[15] = fmaf(w, v3.w, acc[15]);
}

// ---------------------------------------------------------------------------
// K2: fused scores + PV. R5 synthesis of four falsifications:
//  R1: wide (1KB) requests, but 32 VGPRs -> 2 in flight -> serial 400cy pairs.
//  R2: 2x waves, narrow requests -> no BW change (miss queue full).
//  R3: atomics /4 -> no change. R4: 4x per-wave ILP, narrow -> no change.
// => the cap is per-CU outstanding REQUESTS (~20-30); only WIDTH scales BW.
// This kernel: interleaved [4][NSEG][16] q/k/v, batch 4 entries/iter with 32
// dwordx4 (1KB/req) issued before any use, __launch_bounds__(128,1) frees the
// allocator (~200 VGPRs; R4 proved the 2nd arg moves it). 128 thr, lane=wo,
// R0's lean no-LDS structure and atomic epilogue (planar num/den).
// No-max softmax (scores O(+-8); validated).
// ---------------------------------------------------------------------------
__global__ __launch_bounds__(128, 1) void k2_attn(
    const float* __restrict__ q_i, const float* __restrict__ k_i,
    const float* __restrict__ v_i,
    const int4* __restrict__ meta,  const int* __restrict__ row_start,
    float* __restrict__ num, float* __restrict__ den)
{
    const int wo  = threadIdx.x;           // 0..127
    const bool aw = wo < NLON;
    const int woc = aw ? wo : (NLON - 1);
    const int ho  = blockIdx.x;
    const int head = blockIdx.z;           // 0..3
    const int cb  = head * 16;

    int e0 = __builtin_amdgcn_readfirstlane(row_start[ho]);
    int e1 = __builtin_amdgcn_readfirstlane(row_start[ho + 1]);
    int eb = e0 + blockIdx.y * ECH;
    if (eb >= e1) return;
    int ee = eb + ECH; if (ee > e1) ee = e1;

    const int segc = ho * NLON + woc;
    const float4* __restrict__ qp =
        (const float4*)(q_i + (((size_t)head * NSEG + segc) << 4));
    const float4 q0 = qp[0], q1 = qp[1], q2 = qp[2], q3 = qp[3];

    const float* __restrict__ kbase = k_i + (((size_t)head * NSEG) << 4);
    const float* __restrict__ vbase = v_i + (((size_t)head * NSEG) << 4);

    float acc[16];
#pragma unroll
    for (int c = 0; c < 16; ++c) acc[c] = 0.f;
    float dh = 0.f;

    int i = eb;
    for (; i + 4 <= ee; i += 4) {
        int4 m0 = meta[i], m1 = meta[i + 1], m2 = meta[i + 2], m3 = meta[i + 3];
        int p0 = m0.y + woc; if (p0 >= NLON) p0 -= NLON; p0 += m0.x;
        int p1 = m1.y + woc; if (p1 >= NLON) p1 -= NLON; p1 += m1.x;
        int p2 = m2.y + woc; if (p2 >= NLON) p2 -= NLON; p2 += m2.x;
        int p3 = m3.y + woc; if (p3 >= NLON) p3 -= NLON; p3 += m3.x;
        const float4* __restrict__ kp0 = (const float4*)(kbase + ((size_t)p0 << 4));
        const float4* __restrict__ kp1 = (const float4*)(kbase + ((size_t)p1 << 4));
        const float4* __restrict__ kp2 = (const float4*)(kbase + ((size_t)p2 << 4));
        const float4* __restrict__ kp3 = (const float4*)(kbase + ((size_t)p3 << 4));
        const float4* __restrict__ vp0 = (const float4*)(vbase + ((size_t)p0 << 4));
        const float4* __restrict__ vp1 = (const float4*)(vbase + ((size_t)p1 << 4));
        const float4* __restrict__ vp2 = (const float4*)(vbase + ((size_t)p2 << 4));
        const float4* __restrict__ vp3 = (const float4*)(vbase + ((size_t)p3 << 4));

        // 32 x dwordx4: all issued before any consumer -> 32 KB in flight/wave
        float4 ka0 = kp0[0], ka1 = kp0[1], ka2 = kp0[2], ka3 = kp0[3];
        float4 kb0 = kp1[0], kb1 = kp1[1], kb2 = kp1[2], kb3 = kp1[3];
        float4 kc0 = kp2[0], kc1 = kp2[1], kc2 = kp2[2], kc3 = kp2[3];
        float4 kd0 = kp3[0], kd1 = kp3[1], kd2 = kp3[2], kd3 = kp3[3];
        float4 va0 = vp0[0], va1 = vp0[1], va2 = vp0[2], va3 = vp0[3];
        float4 vb0 = vp1[0], vb1 = vp1[1], vb2 = vp1[2], vb3 = vp1[3];
        float4 vc0 = vp2[0], vc1 = vp2[1], vc2 = vp2[2], vc3 = vp2[3];
        float4 vd0 = vp3[0], vd1 = vp3[1], vd2 = vp3[2], vd3 = vp3[3];

        float s0 = dot16(q0, q1, q2, q3, ka0, ka1, ka2, ka3);
        float s1 = dot16(q0, q1, q2, q3, kb0, kb1, kb2, kb3);
        float s2 = dot16(q0, q1, q2, q3, kc0, kc1, kc2, kc3);
        float s3 = dot16(q0, q1, q2, q3, kd0, kd1, kd2, kd3);

        float w0 = __expf(s0) * __int_as_float(m0.z);
        float w1 = __expf(s1) * __int_as_float(m1.z);
        float w2 = __expf(s2) * __int_as_float(m2.z);
        float w3 = __expf(s3) * __int_as_float(m3.z);
        dh += (w0 + w1) + (w2 + w3);

        pv16(w0, va0, va1, va2, va3, acc);
        pv16(w1, vb0, vb1, vb2, vb3, acc);
        pv16(w2, vc0, vc1, vc2, vc3, acc);
        pv16(w3, vd0, vd1, vd2, vd3, acc);
    }
    for (; i < ee; ++i) {                  // tail (<=3 entries)
        int4 mt = meta[i];
        int p = mt.y + woc; if (p >= NLON) p -= NLON; p += mt.x;
        const float4* __restrict__ kp = (const float4*)(kbase + ((size_t)p << 4));
        const float4* __restrict__ vp = (const float4*)(vbase + ((size_t)p << 4));
        float4 k0 = kp[0], k1 = kp[1], k2 = kp[2], k3 = kp[3];
        float4 v0 = vp[0], v1 = vp[1], v2 = vp[2], v3 = vp[3];
        float s = dot16(q0, q1, q2, q3, k0, k1, k2, k3);
        float a = __expf(s) * __int_as_float(mt.z);
        dh += a;
        pv16(a, v0, v1, v2, v3, acc);
    }

    if (aw) {
        const int seg = ho * NLON + wo;
#pragma unroll
        for (int c = 0; c < 16; ++c) atomicAdd(&num[(cb + c) * NSEG + seg], acc[c]);
        atomicAdd(&den[head * NSEG + seg], dh);
    }
}

// ---------------------------------------------------------------------------
// K2c: att = num/den, Wo projection + residual -> x1 planar.
// grid (115, 16): 4 output channels per group.
// ---------------------------------------------------------------------------
__global__ __launch_bounds__(64) void k2c_wo(
    const float* __restrict__ num, const float* __restrict__ den,
    const float* __restrict__ wo,  const float* __restrict__ x,
    float* __restrict__ x1)
{
    const int lane = threadIdx.x;
    const int n    = blockIdx.x * 64 + lane;
    if (n >= NSEG) return;

    float rdh[4];
#pragma unroll
    for (int h = 0; h < 4; ++h) rdh[h] = 1.0f / den[h * NSEG + n];

    float att[64];
#pragma unroll
    for (int c = 0; c < 64; ++c) att[c] = num[c * NSEG + n] * rdh[c >> 4];

    const int o0 = blockIdx.y * 4;
#pragma unroll
    for (int j = 0; j < 4; ++j) {
        int o = o0 + j;
        float acc = 0.f;
#pragma unroll
        for (int c = 0; c < 64; ++c) acc += wo[o * 64 + c] * att[c];
        x1[o * NSEG + n] = acc + x[o * NSEG + n];
    }
}

// ---------------------------------------------------------------------------
// K3a: LayerNorm1 + W1 + exact gelu -> m_act planar [128][NSEG].
// grid (115, 32): 4 hidden units per group.
// ---------------------------------------------------------------------------
__global__ __launch_bounds__(64) void k3a_mlp1(
    const float* __restrict__ x1, const float* __restrict__ w1,
    const float* __restrict__ b1, const float* __restrict__ g,
    const float* __restrict__ bb, float* __restrict__ m_act)
{
    const int lane = threadIdx.x;
    const int n    = blockIdx.x * 64 + lane;
    if (n >= NSEG) return;

    float xv[64];
    float s = 0.f, s2 = 0.f;
#pragma unroll
    for (int c = 0; c < 64; ++c) { float t = x1[c * NSEG + n]; xv[c] = t; s += t; s2 += t * t; }
    float mean = s * 0.015625f;
    float var  = s2 * 0.015625f - mean * mean;
    float rstd = rsqrtf(var + 1e-6f);
#pragma unroll
    for (int c = 0; c < 64; ++c) xv[c] = (xv[c] - mean) * rstd * g[c] + bb[c];

    const int h0 = blockIdx.y * 4;
#pragma unroll
    for (int j = 0; j < 4; ++j) {
        int h = h0 + j;
        float mh = b1[h];
#pragma unroll
        for (int c = 0; c < 64; ++c) mh += w1[h * 64 + c] * xv[c];
        m_act[h * NSEG + n] = 0.5f * mh * (1.0f + erff(mh * 0.70710678118654752f));
    }
}

// ---------------------------------------------------------------------------
// K3b: out = W2 * m_act + b2 + x1. grid (115, 16): 4 output channels/group.
// ---------------------------------------------------------------------------
__global__ __launch_bounds__(64) void k3b_mlp2(
    const float* __restrict__ m_act, const float* __restrict__ w2,
    const float* __restrict__ b2,    const float* __restrict__ x1,
    float* __restrict__ out)
{
    const int lane = threadIdx.x;
    const int n    = blockIdx.x * 64 + lane;
    if (n >= NSEG) return;
    const int c0   = blockIdx.y * 4;

    float acc[4];
#pragma unroll
    for (int j = 0; j < 4; ++j) acc[j] = 0.f;

#pragma unroll 8
    for (int h = 0; h < HIDN; ++h) {
        float mh = m_act[h * NSEG + n];
#pragma unroll
        for (int j = 0; j < 4; ++j) acc[j] += w2[(c0 + j) * HIDN + h] * mh;
    }
#pragma unroll
    for (int j = 0; j < 4; ++j) {
        int c = c0 + j;
        out[c * NSEG + n] = acc[j] + b2[c] + x1[c * NSEG + n];
    }
}

// ---------------------------------------------------------------------------
extern "C" void kernel_launch(void* const* d_in, const int* in_sizes, int n_in,
                              void* d_out, int out_size, void* d_ws, size_t ws_size,
                              hipStream_t stream)
{
    const float* x    = (const float*)d_in[0];
    const float* wq   = (const float*)d_in[1];
    const float* wk   = (const float*)d_in[2];
    const float* wv   = (const float*)d_in[3];
    const float* wo   = (const float*)d_in[4];
    const float* w1   = (const float*)d_in[5];
    const float* b1   = (const float*)d_in[6];
    const float* w2   = (const float*)d_in[7];
    const float* b2   = (const float*)d_in[8];
    const float* ln0g = (const float*)d_in[9];
    const float* ln0b = (const float*)d_in[10];
    const float* ln1g = (const float*)d_in[11];
    const float* ln1b = (const float*)d_in[12];
    const float* qw   = (const float*)d_in[13];
    const int* out_idx = (const int*)d_in[14];
    const int* in_idx  = (const int*)d_in[15];
    float* out = (float*)d_out;

    const int NNZ = in_sizes[15];
    const int E   = NNZ / NLON;
    const size_t N64 = (size_t)NSEG * 64;

    float* ws    = (float*)d_ws;
    float* q_i   = ws;                     // [4][NSEG][16]
    float* k_i   = ws + N64;               // [4][NSEG][16]
    float* v_i   = ws + 2 * N64;           // [4][NSEG][16]
    float* num   = ws + 3 * N64;           // [64][NSEG]  (zeroed by k1)
    float* den   = ws + 4 * N64;           // [4][NSEG]   (zeroed, contiguous w/ num)
    float* x1    = ws + 4 * N64 + 4 * NSEG;
    float* m_act = ws + 5 * N64 + 4 * NSEG;           // [128][NSEG]
    int*   row_start = (int*)(ws + 7 * N64 + 4 * NSEG);            // [62]
    int4*  meta  = (int4*)(ws + 7 * N64 + 4 * NSEG + 64);          // [E]

    hipLaunchKernelGGL(k1_ln_qkv, dim3(115, 15), dim3(64), 0, stream,
                       x, wq, wk, wv, ln0g, ln0b, out_idx, in_idx, qw, E,
                       q_i, k_i, v_i, row_start, meta, (float4*)num);
    hipLaunchKernelGGL(k2_attn, dim3(61, NCH, 4), dim3(128), 0, stream,
                       q_i, k_i, v_i, meta, row_start, num, den);
    hipLaunchKernelGGL(k2c_wo, dim3(115, 16), dim3(64), 0, stream,
                       num, den, wo, x, x1);
    hipLaunchKernelGGL(k3a_mlp1, dim3(115, 32), dim3(64), 0, stream,
                       x1, w1, b1, ln1g, ln1b, m_act);
    hipLaunchKernelGGL(k3b_mlp2, dim3(115, 16), dim3(64), 0, stream,
                       m_act, w2, b2, x1, out);
}